// Round 1
// baseline (619.207 us; speedup 1.0000x reference)
//
#include <hip/hip_runtime.h>
#include <hip/hip_bf16.h>

// ---------- types ----------
typedef __attribute__((ext_vector_type(8))) __bf16 bf16x8;
typedef __attribute__((ext_vector_type(4))) float f32x4;

#define T_SEQ 2048
#define C_DIM 2048
#define QKV_DIM 3072
#define NHEAD 16
#define NKV 4
#define HD 128

__device__ __forceinline__ unsigned short f2bf(float x) {
    __hip_bfloat16 h = __float2bfloat16(x);
    return __builtin_bit_cast(unsigned short, h);
}
__device__ __forceinline__ float bf2f(unsigned short u) {
    unsigned int i = ((unsigned int)u) << 16;
    return __builtin_bit_cast(float, i);
}
__device__ __forceinline__ f32x4 mfma16(bf16x8 a, bf16x8 b, f32x4 c) {
    return __builtin_amdgcn_mfma_f32_16x16x32_bf16(a, b, c, 0, 0, 0);
}

// ---------- elementwise cast x -> bf16 ----------
__global__ __launch_bounds__(256) void cast_f32_to_bf16(
        const float* __restrict__ in, unsigned short* __restrict__ out, int n4) {
    int i = blockIdx.x * 256 + threadIdx.x;
    if (i >= n4) return;
    float4 v = ((const float4*)in)[i];
    ushort4 o;
    o.x = f2bf(v.x); o.y = f2bf(v.y); o.z = f2bf(v.z); o.w = f2bf(v.w);
    ((ushort4*)out)[i] = o;
}

// ---------- cast+transpose fp32 [rows][cols] -> bf16 [cols][rows] ----------
__global__ __launch_bounds__(256) void transpose_cast_f32_bf16(
        const float* __restrict__ in, unsigned short* __restrict__ out,
        int rows, int cols) {
    __shared__ float tile[32][33];
    int c0 = blockIdx.x * 32, r0 = blockIdx.y * 32;
    int tx = threadIdx.x, ty = threadIdx.y;
    #pragma unroll
    for (int i = 0; i < 4; i++)
        tile[ty + 8 * i][tx] = in[(size_t)(r0 + ty + 8 * i) * cols + c0 + tx];
    __syncthreads();
    #pragma unroll
    for (int i = 0; i < 4; i++)
        out[(size_t)(c0 + ty + 8 * i) * rows + r0 + tx] = f2bf(tile[tx][ty + 8 * i]);
}

// ---------- transpose V cols of qkv -> vt[b][kv*128+d][t] ----------
__global__ __launch_bounds__(256) void transpose_v(
        const unsigned short* __restrict__ qkv, unsigned short* __restrict__ vt) {
    __shared__ unsigned short tile[32][33];
    int c0 = blockIdx.x * 32;   // d-col 0..511
    int r0 = blockIdx.y * 32;   // row (b*T+t) 0..4095
    int tx = threadIdx.x, ty = threadIdx.y;
    #pragma unroll
    for (int i = 0; i < 4; i++)
        tile[ty + 8 * i][tx] =
            qkv[(size_t)(r0 + ty + 8 * i) * QKV_DIM + 2560 + c0 + tx];
    __syncthreads();
    #pragma unroll
    for (int i = 0; i < 4; i++) {
        int d = c0 + ty + 8 * i;
        int r = r0 + tx;
        int b = r >> 11, t = r & (T_SEQ - 1);
        vt[(size_t)b * 512 * T_SEQ + (size_t)d * T_SEQ + t] = tile[tx][ty + 8 * i];
    }
}

// ---------- YaRN RoPE in place on q (heads 0..15) and k (heads 16..19) ----------
__global__ __launch_bounds__(256) void rope_kernel(unsigned short* __restrict__ qkv) {
    int row = blockIdx.x;            // b*T + t
    int t = row & (T_SEQ - 1);
    for (int p = threadIdx.x; p < 1280; p += 256) {  // 20 heads * 64 pairs
        int head = p >> 6, i = p & 63;
        // inv_freq = base^(-i/64) / 4   (YaRN scale (8192/2048)^1 = 4, beta=1)
        float inv = 0.25f * exp2f(-(float)i * (13.287712379549449f / 64.0f));
        float ang = (float)t * inv;
        float s, c;
        __sincosf(ang, &s, &c);
        size_t idx = (size_t)row * QKV_DIM + head * 128 + 2 * i;
        float e = bf2f(qkv[idx]), o = bf2f(qkv[idx + 1]);
        qkv[idx]     = f2bf(e * c - o * s);
        qkv[idx + 1] = f2bf(o * c + e * s);
    }
}

// ---------- GEMM: C[M,N] = A[M,K] (bf16) @ Bt[N,K]^T (bf16), fp32 acc ----------
template <int OUT_BF16>
__global__ __launch_bounds__(256) void gemm_bt(
        const unsigned short* __restrict__ A, const unsigned short* __restrict__ Bt,
        void* __restrict__ Cout, int M, int N, int K) {
    __shared__ unsigned short As[128][40];  // +8 pad: 80B row stride, 2-way free
    __shared__ unsigned short Bs[128][40];
    int tid = threadIdx.x;
    int m0 = blockIdx.y * 128, n0 = blockIdx.x * 128;
    int wave = tid >> 6, lane = tid & 63;
    int wm = (wave & 1) * 64, wn = (wave >> 1) * 64;
    int l15 = lane & 15, quad = lane >> 4;

    f32x4 zf = {0.f, 0.f, 0.f, 0.f};
    f32x4 acc[4][4];
    #pragma unroll
    for (int i = 0; i < 4; i++)
        #pragma unroll
        for (int j = 0; j < 4; j++) acc[i][j] = zf;

    for (int k0 = 0; k0 < K; k0 += 32) {
        #pragma unroll
        for (int p = 0; p < 2; p++) {
            int c = tid + p * 256;
            int row = c >> 2, col8 = (c & 3) * 8;
            *(uint4*)&As[row][col8] = *(const uint4*)&A[(size_t)(m0 + row) * K + k0 + col8];
            *(uint4*)&Bs[row][col8] = *(const uint4*)&Bt[(size_t)(n0 + row) * K + k0 + col8];
        }
        __syncthreads();
        bf16x8 af[4], bfr[4];
        #pragma unroll
        for (int i = 0; i < 4; i++)
            af[i] = *(const bf16x8*)&As[wm + i * 16 + l15][quad * 8];
        #pragma unroll
        for (int i = 0; i < 4; i++)
            bfr[i] = *(const bf16x8*)&Bs[wn + i * 16 + l15][quad * 8];
        #pragma unroll
        for (int mi = 0; mi < 4; mi++)
            #pragma unroll
            for (int ni = 0; ni < 4; ni++)
                acc[mi][ni] = mfma16(af[mi], bfr[ni], acc[mi][ni]);
        __syncthreads();
    }
    #pragma unroll
    for (int mi = 0; mi < 4; mi++)
        #pragma unroll
        for (int ni = 0; ni < 4; ni++) {
            int row = m0 + wm + mi * 16 + quad * 4;
            int col = n0 + wn + ni * 16 + l15;
            #pragma unroll
            for (int r = 0; r < 4; r++) {
                float v = acc[mi][ni][r];
                if (OUT_BF16)
                    ((unsigned short*)Cout)[(size_t)(row + r) * N + col] = f2bf(v);
                else
                    ((float*)Cout)[(size_t)(row + r) * N + col] = v;
            }
        }
}

// ---------- flash attention: 1 wave per (b, h, 16 q-rows) ----------
__global__ __launch_bounds__(64) void attn_kernel(
        const unsigned short* __restrict__ qkv, const unsigned short* __restrict__ vt,
        unsigned short* __restrict__ attn_out) {
    __shared__ unsigned short p_lds[16][32];
    int bid = blockIdx.x;
    int qt = bid & 127;
    int h = (bid >> 7) & 15;
    int b = bid >> 11;
    int kv = h >> 2;                 // GQA: jnp.repeat -> kv = h // 4
    int lane = threadIdx.x;
    int l15 = lane & 15, quad = lane >> 4;

    // Q fragments: A[m=l15][k = c*32 + quad*8 + j]
    const unsigned short* qbase =
        qkv + (size_t)(b * T_SEQ + qt * 16 + l15) * QKV_DIM + h * HD;
    bf16x8 aq[4];
    #pragma unroll
    for (int c = 0; c < 4; c++) aq[c] = *(const bf16x8*)(qbase + c * 32 + quad * 8);

    const unsigned short* kbase = qkv + (size_t)(b * T_SEQ) * QKV_DIM + 2048 + kv * HD;
    const unsigned short* vbase = vt + (size_t)(b * NKV + kv) * HD * T_SEQ;

    f32x4 zf = {0.f, 0.f, 0.f, 0.f};
    float m_r[4], l_r[4];
    f32x4 oacc[8];
    #pragma unroll
    for (int r = 0; r < 4; r++) { m_r[r] = -1e30f; l_r[r] = 0.f; }
    #pragma unroll
    for (int d = 0; d < 8; d++) oacc[d] = zf;

    const float inv_sqrt_d = 0.08838834764831845f;  // 1/sqrt(128)
    int kmax = qt * 16 + 16;
    for (int k0 = 0; k0 < kmax; k0 += 32) {
        // S = Q @ K^T for 32 keys (two 16-col tiles)
        f32x4 s0 = zf, s1 = zf;
        const unsigned short* k0p = kbase + (size_t)(k0 + l15) * QKV_DIM + quad * 8;
        const unsigned short* k1p = kbase + (size_t)(k0 + 16 + l15) * QKV_DIM + quad * 8;
        #pragma unroll
        for (int c = 0; c < 4; c++) {
            bf16x8 bk0 = *(const bf16x8*)(k0p + c * 32);
            bf16x8 bk1 = *(const bf16x8*)(k1p + c * 32);
            s0 = mfma16(aq[c], bk0, s0);
            s1 = mfma16(aq[c], bk1, s1);
        }
        int key0 = k0 + l15, key1 = k0 + 16 + l15;
        float p0[4], p1[4], alpha[4];
        #pragma unroll
        for (int r = 0; r < 4; r++) {
            int qrow = qt * 16 + quad * 4 + r;
            float v0 = s0[r] * inv_sqrt_d;
            float v1 = s1[r] * inv_sqrt_d;
            // softcap 50*tanh(v/50) = 50*(e-1)/(e+1), e = exp(2v/50)
            float e0 = __expf(v0 * 0.04f);
            float e1 = __expf(v1 * 0.04f);
            v0 = 50.f * ((e0 - 1.f) / (e0 + 1.f));
            v1 = 50.f * ((e1 - 1.f) / (e1 + 1.f));
            if (key0 > qrow) v0 = -1e9f;   // causal mask AFTER softcap (ref order)
            if (key1 > qrow) v1 = -1e9f;
            float mt = fmaxf(v0, v1);
            #pragma unroll
            for (int off = 1; off < 16; off <<= 1) mt = fmaxf(mt, __shfl_xor(mt, off));
            float mnew = fmaxf(m_r[r], mt);
            float al = __expf(m_r[r] - mnew);
            float pe0 = __expf(v0 - mnew);
            float pe1 = __expf(v1 - mnew);
            float rs = pe0 + pe1;
            #pragma unroll
            for (int off = 1; off < 16; off <<= 1) rs += __shfl_xor(rs, off);
            l_r[r] = l_r[r] * al + rs;
            m_r[r] = mnew;
            alpha[r] = al;
            p0[r] = pe0; p1[r] = pe1;
        }
        #pragma unroll
        for (int d = 0; d < 8; d++) {
            oacc[d][0] *= alpha[0]; oacc[d][1] *= alpha[1];
            oacc[d][2] *= alpha[2]; oacc[d][3] *= alpha[3];
        }
        // P: C-layout -> A-layout via LDS round-trip
        __syncthreads();
        #pragma unroll
        for (int r = 0; r < 4; r++) {
            p_lds[quad * 4 + r][l15] = f2bf(p0[r]);
            p_lds[quad * 4 + r][16 + l15] = f2bf(p1[r]);
        }
        __syncthreads();
        bf16x8 ap = *(const bf16x8*)&p_lds[l15][quad * 8];
        // O += P @ V ; B[k=key][n=dim] read from vt rows (contiguous in key)
        #pragma unroll
        for (int d = 0; d < 8; d++) {
            bf16x8 bv = *(const bf16x8*)(vbase + (size_t)(d * 16 + l15) * T_SEQ + k0 + quad * 8);
            oacc[d] = mfma16(ap, bv, oacc[d]);
        }
    }
    #pragma unroll
    for (int d = 0; d < 8; d++) {
        #pragma unroll
        for (int r = 0; r < 4; r++) {
            int grow = b * T_SEQ + qt * 16 + quad * 4 + r;
            attn_out[(size_t)grow * C_DIM + h * HD + d * 16 + l15] =
                f2bf(oacc[d][r] / l_r[r]);
        }
    }
}

extern "C" void kernel_launch(void* const* d_in, const int* in_sizes, int n_in,
                              void* d_out, int out_size, void* d_ws, size_t ws_size,
                              hipStream_t stream) {
    (void)in_sizes; (void)n_in; (void)out_size; (void)ws_size;
    const float* x = (const float*)d_in[0];
    const float* w_qkv = (const float*)d_in[1];
    const float* w_o = (const float*)d_in[2];
    char* ws = (char*)d_ws;

    unsigned short* xbf   = (unsigned short*)(ws);                       // 16 MB
    unsigned short* wqkvT = (unsigned short*)(ws + 16777216);            // 12 MB
    unsigned short* woT   = (unsigned short*)(ws + 29360128);            //  8 MB
    unsigned short* qkv   = (unsigned short*)(ws + 37748736);            // 24 MB
    unsigned short* vt    = (unsigned short*)(ws + 62914560);            //  4 MB -> 64 MB total
    unsigned short* attn  = xbf;  // xbf dead after gemm1; reuse for attention out

    cast_f32_to_bf16<<<8192, 256, 0, stream>>>(x, xbf, 2097152);
    transpose_cast_f32_bf16<<<dim3(96, 64), dim3(32, 8), 0, stream>>>(w_qkv, wqkvT, 2048, 3072);
    transpose_cast_f32_bf16<<<dim3(64, 64), dim3(32, 8), 0, stream>>>(w_o, woT, 2048, 2048);
    gemm_bt<1><<<dim3(24, 32), 256, 0, stream>>>(xbf, wqkvT, qkv, 4096, 3072, 2048);
    rope_kernel<<<4096, 256, 0, stream>>>(qkv);
    transpose_v<<<dim3(16, 128), dim3(32, 8), 0, stream>>>(qkv, vt);
    attn_kernel<<<4096, 64, 0, stream>>>(qkv, vt, attn);
    gemm_bt<0><<<dim3(16, 32), 256, 0, stream>>>(attn, woT, d_out, 4096, 2048, 2048);
}

// Round 2
// 481.289 us; speedup vs baseline: 1.2866x; 1.2866x over previous
//
#include <hip/hip_runtime.h>
#include <hip/hip_bf16.h>

// ---------- types ----------
typedef __attribute__((ext_vector_type(8))) __bf16 bf16x8;
typedef __attribute__((ext_vector_type(4))) float f32x4;

#define T_SEQ 2048
#define C_DIM 2048
#define QKV_DIM 3072
#define NKV 4
#define HD 128

#define AS1 __attribute__((address_space(1)))
#define AS3 __attribute__((address_space(3)))

__device__ __forceinline__ unsigned short f2bf(float x) {
    __hip_bfloat16 h = __float2bfloat16(x);
    return __builtin_bit_cast(unsigned short, h);
}
__device__ __forceinline__ float bf2f(unsigned short u) {
    unsigned int i = ((unsigned int)u) << 16;
    return __builtin_bit_cast(float, i);
}
__device__ __forceinline__ unsigned int pk2(float lo, float hi) {
    return ((unsigned int)f2bf(hi) << 16) | (unsigned int)f2bf(lo);
}
__device__ __forceinline__ f32x4 mfma16(bf16x8 a, bf16x8 b, f32x4 c) {
    return __builtin_amdgcn_mfma_f32_16x16x32_bf16(a, b, c, 0, 0, 0);
}
__device__ __forceinline__ void gload_lds16(const void* g, void* l) {
    __builtin_amdgcn_global_load_lds((const AS1 unsigned int*)g,
                                     (AS3 unsigned int*)l, 16, 0, 0);
}

// ---------- elementwise cast x -> bf16 ----------
__global__ __launch_bounds__(256) void cast_f32_to_bf16(
        const float* __restrict__ in, unsigned short* __restrict__ out, int n4) {
    int i = blockIdx.x * 256 + threadIdx.x;
    if (i >= n4) return;
    float4 v = ((const float4*)in)[i];
    ushort4 o;
    o.x = f2bf(v.x); o.y = f2bf(v.y); o.z = f2bf(v.z); o.w = f2bf(v.w);
    ((ushort4*)out)[i] = o;
}

// ---------- cast+transpose fp32 [rows][cols] -> bf16 [cols][rows] ----------
__global__ __launch_bounds__(256) void transpose_cast_f32_bf16(
        const float* __restrict__ in, unsigned short* __restrict__ out,
        int rows, int cols) {
    __shared__ float tile[32][33];
    int c0 = blockIdx.x * 32, r0 = blockIdx.y * 32;
    int tx = threadIdx.x, ty = threadIdx.y;
    #pragma unroll
    for (int i = 0; i < 4; i++)
        tile[ty + 8 * i][tx] = in[(size_t)(r0 + ty + 8 * i) * cols + c0 + tx];
    __syncthreads();
    #pragma unroll
    for (int i = 0; i < 4; i++)
        out[(size_t)(c0 + ty + 8 * i) * rows + r0 + tx] = f2bf(tile[tx][ty + 8 * i]);
}

// ---------- transpose V cols of qkv -> vt[b][kv*128+d][t] ----------
__global__ __launch_bounds__(256) void transpose_v(
        const unsigned short* __restrict__ qkv, unsigned short* __restrict__ vt) {
    __shared__ unsigned short tile[32][33];
    int c0 = blockIdx.x * 32;   // d-col 0..511
    int r0 = blockIdx.y * 32;   // row (b*T+t) 0..4095
    int tx = threadIdx.x, ty = threadIdx.y;
    #pragma unroll
    for (int i = 0; i < 4; i++)
        tile[ty + 8 * i][tx] =
            qkv[(size_t)(r0 + ty + 8 * i) * QKV_DIM + 2560 + c0 + tx];
    __syncthreads();
    #pragma unroll
    for (int i = 0; i < 4; i++) {
        int d = c0 + ty + 8 * i;
        int r = r0 + tx;
        int b = r >> 11, t = r & (T_SEQ - 1);
        vt[(size_t)b * 512 * T_SEQ + (size_t)d * T_SEQ + t] = tile[tx][ty + 8 * i];
    }
}

// ---------- YaRN RoPE in place on q (heads 0..15) and k (heads 16..19) ----------
__global__ __launch_bounds__(256) void rope_kernel(unsigned short* __restrict__ qkv) {
    int row = blockIdx.x;            // b*T + t
    int t = row & (T_SEQ - 1);
    for (int p = threadIdx.x; p < 1280; p += 256) {  // 20 heads * 64 pairs
        int head = p >> 6, i = p & 63;
        float inv = 0.25f * exp2f(-(float)i * (13.287712379549449f / 64.0f));
        float ang = (float)t * inv;
        float s, c;
        __sincosf(ang, &s, &c);
        size_t idx = (size_t)row * QKV_DIM + head * 128 + 2 * i;
        float e = bf2f(qkv[idx]), o = bf2f(qkv[idx + 1]);
        qkv[idx]     = f2bf(e * c - o * s);
        qkv[idx + 1] = f2bf(o * c + e * s);
    }
}

// ---------- GEMM (m97 structure): C[M,N] = A[M,K] @ Bt[N,K]^T ----------
template <int OUT_BF16>
__global__ __launch_bounds__(256) void gemm_bt(
        const unsigned short* __restrict__ A, const unsigned short* __restrict__ Bt,
        void* __restrict__ Cout, int M, int N, int K) {
    // unpadded: global_load_lds needs LDS dest = uniform base + lane*16
    __shared__ __align__(16) unsigned short As[128 * 32];
    __shared__ __align__(16) unsigned short Bs[128 * 32];
    int tid = threadIdx.x;
    int m0 = blockIdx.y * 128, n0 = blockIdx.x * 128;
    int wave = tid >> 6, lane = tid & 63;
    int wm = (wave & 1) * 64, wn = (wave >> 1) * 64;
    int l15 = lane & 15, quad = lane >> 4;
    int lrow = lane >> 2, lcol = (lane & 3) * 8;   // staging map: lane*16B

    f32x4 zf = {0.f, 0.f, 0.f, 0.f};
    f32x4 acc[4][4];
    #pragma unroll
    for (int i = 0; i < 4; i++)
        #pragma unroll
        for (int j = 0; j < 4; j++) acc[i][j] = zf;

    int ca = wave * 2;  // this wave's two 16-row chunks (of 8)
    const unsigned short* gA = A + (size_t)(m0 + ca * 16 + lrow) * K + lcol;
    const unsigned short* gB = Bt + (size_t)(n0 + ca * 16 + lrow) * K + lcol;

    for (int k0 = 0; k0 < K; k0 += 32) {
        gload_lds16(gA + k0, &As[ca * 512]);
        gload_lds16(gA + k0 + 16 * (size_t)K, &As[ca * 512 + 512]);
        gload_lds16(gB + k0, &Bs[ca * 512]);
        gload_lds16(gB + k0 + 16 * (size_t)K, &Bs[ca * 512 + 512]);
        __syncthreads();
        bf16x8 af[4], bfr[4];
        #pragma unroll
        for (int i = 0; i < 4; i++)
            af[i] = *(const bf16x8*)&As[(wm + i * 16 + l15) * 32 + quad * 8];
        #pragma unroll
        for (int i = 0; i < 4; i++)
            bfr[i] = *(const bf16x8*)&Bs[(wn + i * 16 + l15) * 32 + quad * 8];
        #pragma unroll
        for (int mi = 0; mi < 4; mi++)
            #pragma unroll
            for (int ni = 0; ni < 4; ni++)
                acc[mi][ni] = mfma16(af[mi], bfr[ni], acc[mi][ni]);
        __syncthreads();
    }
    #pragma unroll
    for (int mi = 0; mi < 4; mi++)
        #pragma unroll
        for (int ni = 0; ni < 4; ni++) {
            int row = m0 + wm + mi * 16 + quad * 4;
            int col = n0 + wn + ni * 16 + l15;
            #pragma unroll
            for (int r = 0; r < 4; r++) {
                float v = acc[mi][ni][r];
                if (OUT_BF16)
                    ((unsigned short*)Cout)[(size_t)(row + r) * N + col] = f2bf(v);
                else
                    ((float*)Cout)[(size_t)(row + r) * N + col] = v;
            }
        }
}

// ---------- flash attention, S^T formulation, no-max softmax ----------
// One wave handles one 16-row q-tile; kernel runs the balanced pair (j, 127-j).
__device__ __forceinline__ void attn_tile(
        const unsigned short* __restrict__ qkv, const unsigned short* __restrict__ vt,
        unsigned short* __restrict__ attn_out, unsigned int* pT,
        int b, int h, int qt, int lane) {
    int l15 = lane & 15, quad = lane >> 4;
    int kv = h >> 2;
    f32x4 zf = {0.f, 0.f, 0.f, 0.f};

    // Q B-frag (== A-frag layout): Q[qrow=l15][k=c*32+quad*8+j]
    const unsigned short* qp =
        qkv + (size_t)(b * T_SEQ + qt * 16 + l15) * QKV_DIM + h * HD + quad * 8;
    bf16x8 aq[4];
    #pragma unroll
    for (int c = 0; c < 4; c++) aq[c] = *(const bf16x8*)(qp + c * 32);

    const unsigned short* kbase = qkv + (size_t)b * T_SEQ * QKV_DIM + 2048 + kv * HD;
    const unsigned short* vbase = vt + (size_t)(b * NKV + kv) * HD * T_SEQ;

    f32x4 oacc[8];
    #pragma unroll
    for (int d = 0; d < 8; d++) oacc[d] = zf;
    float lsum = 0.f;

    int qglob = qt * 16 + l15;   // this lane's q-row (S^T col)
    int kmax = qt * 16 + 16;
    for (int k0 = 0; k0 < kmax; k0 += 32) {
        // S^T = K·Q^T : two 16-key tiles
        f32x4 s0 = zf, s1 = zf;
        const unsigned short* kp0 = kbase + (size_t)(k0 + l15) * QKV_DIM + quad * 8;
        const unsigned short* kp1 = kp0 + (size_t)16 * QKV_DIM;
        #pragma unroll
        for (int c = 0; c < 4; c++) {
            bf16x8 a0 = *(const bf16x8*)(kp0 + c * 32);
            bf16x8 a1 = *(const bf16x8*)(kp1 + c * 32);
            s0 = mfma16(a0, aq[c], s0);
            s1 = mfma16(a1, aq[c], s1);
        }
        // softcap + exp (no max subtraction; scores capped to +-50)
        float p0[4], p1[4];
        #pragma unroll
        for (int r = 0; r < 4; r++) {
            int key0 = k0 + quad * 4 + r;
            float v0 = s0[r] * 0.08838834764831845f;
            float v1 = s1[r] * 0.08838834764831845f;
            float e0 = __expf(v0 * 0.04f);
            float e1 = __expf(v1 * 0.04f);
            float t0 = 50.f * (e0 - 1.f) * __builtin_amdgcn_rcpf(e0 + 1.f);
            float t1 = 50.f * (e1 - 1.f) * __builtin_amdgcn_rcpf(e1 + 1.f);
            p0[r] = (key0 <= qglob) ? __expf(t0) : 0.f;
            p1[r] = (key0 + 16 <= qglob) ? __expf(t1) : 0.f;
            lsum += p0[r] + p1[r];
        }
        // P^T transpose via LDS (single wave: in-order LDS, no barrier)
        unsigned int d0 = pk2(p0[0], p0[1]), d1 = pk2(p0[2], p0[3]);
        unsigned int d2 = pk2(p1[0], p1[1]), d3 = pk2(p1[2], p1[3]);
        unsigned int* wp = pT + l15 * 20 + quad * 2;   // [qrow][kp], stride 20 dwords
        *(uint2*)wp = make_uint2(d0, d1);
        *(uint2*)(wp + 8) = make_uint2(d2, d3);
        __asm__ volatile("s_waitcnt lgkmcnt(0)" ::: "memory");
        bf16x8 bp = *(const bf16x8*)(pT + l15 * 20 + quad * 4);  // B-frag of P^T
        // O^T += V^T · P^T
        const unsigned short* vp = vbase + (size_t)l15 * T_SEQ + k0 + quad * 8;
        #pragma unroll
        for (int dd = 0; dd < 8; dd++) {
            bf16x8 av = *(const bf16x8*)(vp + (size_t)dd * 16 * T_SEQ);
            oacc[dd] = mfma16(av, bp, oacc[dd]);
        }
        __asm__ volatile("" ::: "memory");  // keep next-iter LDS writes after read
    }
    // l(qrow=l15): combine the 4 quads
    float l = lsum;
    l += __shfl_xor(l, 16);
    l += __shfl_xor(l, 32);
    float rl = __builtin_amdgcn_rcpf(l);
    // O^T acc: row=quad*4+r = d_local, col=l15 = qrow
    unsigned short* op = attn_out +
        (size_t)(b * T_SEQ + qt * 16 + l15) * C_DIM + h * HD + quad * 4;
    #pragma unroll
    for (int dd = 0; dd < 8; dd++) {
        ushort4 o;
        o.x = f2bf(oacc[dd][0] * rl);
        o.y = f2bf(oacc[dd][1] * rl);
        o.z = f2bf(oacc[dd][2] * rl);
        o.w = f2bf(oacc[dd][3] * rl);
        *(ushort4*)(op + dd * 16) = o;
    }
}

__global__ __launch_bounds__(64) void attn_kernel(
        const unsigned short* __restrict__ qkv, const unsigned short* __restrict__ vt,
        unsigned short* __restrict__ attn_out) {
    __shared__ __align__(16) unsigned int pT[16 * 20];
    int bid = blockIdx.x;
    int j = bid & 63, h = (bid >> 6) & 15, b = bid >> 10;
    int lane = threadIdx.x;
    attn_tile(qkv, vt, attn_out, pT, b, h, j, lane);        // short tile
    attn_tile(qkv, vt, attn_out, pT, b, h, 127 - j, lane);  // long tile: sum = 65
}

extern "C" void kernel_launch(void* const* d_in, const int* in_sizes, int n_in,
                              void* d_out, int out_size, void* d_ws, size_t ws_size,
                              hipStream_t stream) {
    (void)in_sizes; (void)n_in; (void)out_size; (void)ws_size;
    const float* x = (const float*)d_in[0];
    const float* w_qkv = (const float*)d_in[1];
    const float* w_o = (const float*)d_in[2];
    char* ws = (char*)d_ws;

    unsigned short* xbf   = (unsigned short*)(ws);                       // 16 MB
    unsigned short* wqkvT = (unsigned short*)(ws + 16777216);            // 12 MB
    unsigned short* woT   = (unsigned short*)(ws + 29360128);            //  8 MB
    unsigned short* qkv   = (unsigned short*)(ws + 37748736);            // 24 MB
    unsigned short* vt    = (unsigned short*)(ws + 62914560);            //  4 MB -> 64 MB
    unsigned short* attn  = xbf;  // xbf dead after gemm1

    cast_f32_to_bf16<<<8192, 256, 0, stream>>>(x, xbf, 2097152);
    transpose_cast_f32_bf16<<<dim3(96, 64), dim3(32, 8), 0, stream>>>(w_qkv, wqkvT, 2048, 3072);
    transpose_cast_f32_bf16<<<dim3(64, 64), dim3(32, 8), 0, stream>>>(w_o, woT, 2048, 2048);
    gemm_bt<1><<<dim3(24, 32), 256, 0, stream>>>(xbf, wqkvT, qkv, 4096, 3072, 2048);
    rope_kernel<<<4096, 256, 0, stream>>>(qkv);
    transpose_v<<<dim3(16, 128), dim3(32, 8), 0, stream>>>(qkv, vt);
    attn_kernel<<<2048, 64, 0, stream>>>(qkv, vt, attn);
    gemm_bt<0><<<dim3(16, 32), 256, 0, stream>>>(attn, woT, d_out, 4096, 2048, 2048);
}